// Round 1
// baseline (63.214 us; speedup 1.0000x reference)
//
#include <hip/hip_runtime.h>

// TreeGCN fused kernel for MI355X (gfx950).
// B=64, NODES=512, DEG=8, IN_F=64, OUT_F=64, SUP=640.
// Key algebraic opt: Ws = Ws1@Ws2 precomputed (no nonlinearity between) ->
// support MLP collapses from 27.5 GF to 2.1 GF. Everything else bf16 MFMA.

typedef float f32x4 __attribute__((ext_vector_type(4)));
typedef __bf16 bf16x8 __attribute__((ext_vector_type(8)));

__device__ __forceinline__ unsigned short f2bf(float f) {
    union { float f; unsigned int u; } x; x.f = f;
    unsigned int r = x.u + 0x7FFFu + ((x.u >> 16) & 1u);
    return (unsigned short)(r >> 16);
}

#define LDP 72  // bf16 row stride: 144 B -> even 8-way bank spread for b128 frag reads

// ---------------- prep: ylow (levels 0-2 at n/8 granularity) + WsF^T bf16 ----
__global__ __launch_bounds__(256) void tree_prep(
    const float* __restrict__ x0, const float* __restrict__ W0,
    const float* __restrict__ x1, const float* __restrict__ W1,
    const float* __restrict__ x2, const float* __restrict__ W2,
    const float* __restrict__ Ws1, const float* __restrict__ Ws2,
    float* __restrict__ ylow, unsigned short* __restrict__ wsW)
{
    const int t = threadIdx.x;
    if (blockIdx.x < 64) {
        // ---- ylow[b][g][f] = x0@W0 + x1@W1 + x2@W2 (g = node>>3), fp32 exact
        __shared__ float XT2[64 * 68];   // x2[b] transposed [k][g]
        __shared__ float x1s[512];
        __shared__ float x0s[96];
        __shared__ float lvl[512];       // lvl01[h][f]
        const int b = blockIdx.x;
        if (t < 96) x0s[t] = x0[b * 96 + t];
        x1s[t]       = x1[b * 512 + t];
        x1s[256 + t] = x1[b * 512 + 256 + t];
        {
            const int g = t & 63, kq = t >> 6;
            const float* src = x2 + (size_t)b * 4096 + g * 64 + kq * 16;
            float tmp[16];
            #pragma unroll
            for (int i = 0; i < 4; ++i) {
                float4 v = *(const float4*)(src + 4 * i);
                tmp[4*i+0] = v.x; tmp[4*i+1] = v.y; tmp[4*i+2] = v.z; tmp[4*i+3] = v.w;
            }
            #pragma unroll
            for (int i = 0; i < 16; ++i) XT2[(kq * 16 + i) * 68 + g] = tmp[i];
        }
        __syncthreads();
        {
            const int f = t & 63, h0 = t >> 6;
            float acc0 = 0.f;
            for (int k = 0; k < 96; ++k) acc0 += x0s[k] * W0[k * 64 + f];
            #pragma unroll
            for (int s = 0; s < 2; ++s) {
                const int hh = h0 + 4 * s;
                float a = acc0;
                for (int k = 0; k < 64; ++k) a += x1s[hh * 64 + k] * W1[k * 64 + f];
                lvl[hh * 64 + f] = a;
            }
        }
        __syncthreads();
        {
            const int g0 = 4 * (t >> 4), f0 = 4 * (t & 15);
            float acc[4][4];
            float lv[4];
            #pragma unroll
            for (int j = 0; j < 4; ++j) lv[j] = lvl[(g0 >> 3) * 64 + f0 + j];
            #pragma unroll
            for (int i = 0; i < 4; ++i)
                #pragma unroll
                for (int j = 0; j < 4; ++j) acc[i][j] = lv[j];
            for (int k = 0; k < 64; ++k) {
                float4 a = *(const float4*)&XT2[k * 68 + g0];
                float4 wv = *(const float4*)(W2 + k * 64 + f0);
                const float ap[4] = {a.x, a.y, a.z, a.w};
                const float wp[4] = {wv.x, wv.y, wv.z, wv.w};
                #pragma unroll
                for (int i = 0; i < 4; ++i)
                    #pragma unroll
                    for (int j = 0; j < 4; ++j) acc[i][j] += ap[i] * wp[j];
            }
            #pragma unroll
            for (int i = 0; i < 4; ++i) {
                float4 st = make_float4(acc[i][0], acc[i][1], acc[i][2], acc[i][3]);
                *(float4*)(ylow + (size_t)b * 4096 + (size_t)(g0 + i) * 64 + f0) = st;
            }
        }
    } else {
        // ---- WsF^T[f][c] = (Ws1@Ws2)[c][f] as bf16; block = one f row
        const int f = blockIdx.x - 64;
        const int c = t >> 2, q = t & 3;
        const float* w1p = Ws1 + (size_t)c * 640 + q * 160;
        const float* w2p = Ws2 + (size_t)q * 160 * 64 + f;
        float acc = 0.f;
        #pragma unroll 4
        for (int s = 0; s < 160; ++s) acc += w1p[s] * w2p[(size_t)s * 64];
        acc += __shfl_xor(acc, 1, 64);
        acc += __shfl_xor(acc, 2, 64);
        if (q == 0) wsW[f * 64 + c] = f2bf(acc);
    }
}

// ---------------- main: per-node fused branch-GEMM + support + epilogue ------
__global__ __launch_bounds__(256, 2) void tree_main(
    const float* __restrict__ x3, const float* __restrict__ W3,
    const float* __restrict__ branch, const float* __restrict__ bias,
    const float* __restrict__ ylow, const unsigned short* __restrict__ wsW,
    float* __restrict__ out)
{
    __shared__ unsigned short Xs[64 * LDP];  // bf16 X [b][k]
    __shared__ unsigned short Bt[64 * LDP];  // bf16 branch-slice^T [c][k] (W3^T at start)
    __shared__ unsigned short Ts[64 * LDP];  // bf16 T [b][c] (wave-private 16-row slices)
    __shared__ unsigned short Wt[64 * LDP];  // bf16 WsF^T [f][c]

    const int t = threadIdx.x;
    const int l = t & 63;
    const int w = t >> 6;
    const int n = blockIdx.x;
    const int l15 = l & 15;
    const int l4 = l >> 4;

    const int rk = t & 15;   // transpose-stage: k-quad
    const int rc = t >> 4;   // transpose-stage: c-quad (0..15)
    const float* brn = branch + (size_t)n * 32768;

    // prefetch d=0 branch slice into registers
    float4 pf[4];
    #pragma unroll
    for (int i = 0; i < 4; ++i)
        pf[i] = *(const float4*)(brn + (size_t)(4 * rk + i) * 512 + 4 * rc);

    // stage Xs = bf16(x3[:, n, :]) [b][k]
    {
        const float* src = x3 + (size_t)l * 32768 + (size_t)n * 64 + w * 16;
        float tmp[16];
        #pragma unroll
        for (int i = 0; i < 4; ++i) {
            float4 v = *(const float4*)(src + 4 * i);
            tmp[4*i+0] = v.x; tmp[4*i+1] = v.y; tmp[4*i+2] = v.z; tmp[4*i+3] = v.w;
        }
        union { unsigned short h[8]; uint4 u; } p0, p1;
        #pragma unroll
        for (int j = 0; j < 8; ++j) { p0.h[j] = f2bf(tmp[j]); p1.h[j] = f2bf(tmp[8 + j]); }
        *(uint4*)&Xs[l * LDP + w * 16]     = p0.u;
        *(uint4*)&Xs[l * LDP + w * 16 + 8] = p1.u;
    }
    // stage Wt = WsF^T (already bf16)
    {
        const int f = t >> 2, cq = t & 3;
        *(uint4*)&Wt[f * LDP + cq * 16]     = *(const uint4*)(wsW + f * 64 + cq * 16);
        *(uint4*)&Wt[f * LDP + cq * 16 + 8] = *(const uint4*)(wsW + f * 64 + cq * 16 + 8);
    }
    // stage Bt = W3^T [f][k] (transpose from W3[k][f])
    {
        float vv[4][4];
        #pragma unroll
        for (int i = 0; i < 4; ++i) {
            float4 v = *(const float4*)(W3 + (size_t)(4 * rk + i) * 64 + 4 * rc);
            vv[i][0] = v.x; vv[i][1] = v.y; vv[i][2] = v.z; vv[i][3] = v.w;
        }
        #pragma unroll
        for (int ci = 0; ci < 4; ++ci) {
            union { unsigned short h[4]; uint2 u; } qq;
            #pragma unroll
            for (int i = 0; i < 4; ++i) qq.h[i] = f2bf(vv[i][ci]);
            *(uint2*)&Bt[(4 * rc + ci) * LDP + 4 * rk] = qq.u;
        }
    }
    __syncthreads();

    // hoisted fragments: A (this wave's 16 batch rows of X), B (WsF^T)
    bf16x8 af[2];
    #pragma unroll
    for (int ks = 0; ks < 2; ++ks)
        af[ks] = *(const bf16x8*)&Xs[(16 * w + l15) * LDP + 32 * ks + l4 * 8];

    bf16x8 wfrag[4][2];
    #pragma unroll
    for (int ft = 0; ft < 4; ++ft) {
        #pragma unroll
        for (int ks = 0; ks < 2; ++ks)
            wfrag[ft][ks] = *(const bf16x8*)&Wt[(16 * ft + l15) * LDP + 32 * ks + l4 * 8];
    }

    // Y = X@W3 + ylow, kept in registers (same thread->(b,f) mapping as GEMM2)
    f32x4 y[4];
    #pragma unroll
    for (int ft = 0; ft < 4; ++ft) {
        bf16x8 b0 = *(const bf16x8*)&Bt[(16 * ft + l15) * LDP + l4 * 8];
        bf16x8 b1 = *(const bf16x8*)&Bt[(16 * ft + l15) * LDP + 32 + l4 * 8];
        f32x4 acc = {0.f, 0.f, 0.f, 0.f};
        acc = __builtin_amdgcn_mfma_f32_16x16x32_bf16(af[0], b0, acc, 0, 0, 0);
        acc = __builtin_amdgcn_mfma_f32_16x16x32_bf16(af[1], b1, acc, 0, 0, 0);
        y[ft] = acc;
    }
    {
        const float* yl = ylow + (size_t)(n >> 3) * 64;
        #pragma unroll
        for (int ft = 0; ft < 4; ++ft) {
            #pragma unroll
            for (int r = 0; r < 4; ++r)
                y[ft][r] += yl[(size_t)(16 * w + 4 * l4 + r) * 4096 + 16 * ft + l15];
        }
    }
    __syncthreads();  // W3^T reads done; Bt reusable

    for (int d = 0; d < 8; ++d) {
        // write Bt = bf16(branch[n][:, d*64:+64])^T [c][k] from prefetched regs
        #pragma unroll
        for (int ci = 0; ci < 4; ++ci) {
            union { unsigned short h[4]; uint2 u; } qq;
            #pragma unroll
            for (int i = 0; i < 4; ++i) qq.h[i] = f2bf(((const float*)&pf[i])[ci]);
            *(uint2*)&Bt[(4 * rc + ci) * LDP + 4 * rk] = qq.u;
        }
        __syncthreads();

        // GEMM1: S = X @ Br_d   (this wave: batch rows 16w..16w+15, all 64 c)
        f32x4 s[4];
        #pragma unroll
        for (int ct = 0; ct < 4; ++ct) {
            bf16x8 b0 = *(const bf16x8*)&Bt[(16 * ct + l15) * LDP + l4 * 8];
            bf16x8 b1 = *(const bf16x8*)&Bt[(16 * ct + l15) * LDP + 32 + l4 * 8];
            f32x4 acc = {0.f, 0.f, 0.f, 0.f};
            acc = __builtin_amdgcn_mfma_f32_16x16x32_bf16(af[0], b0, acc, 0, 0, 0);
            acc = __builtin_amdgcn_mfma_f32_16x16x32_bf16(af[1], b1, acc, 0, 0, 0);
            s[ct] = acc;
        }
        // lrelu -> bf16 -> Ts[b][c]  (lrelu(x) == max(x, 0.2x))
        #pragma unroll
        for (int ct = 0; ct < 4; ++ct) {
            #pragma unroll
            for (int r = 0; r < 4; ++r) {
                float v = s[ct][r];
                v = fmaxf(v, 0.2f * v);
                Ts[(16 * w + 4 * l4 + r) * LDP + 16 * ct + l15] = f2bf(v);
            }
        }
        __syncthreads();

        // prefetch next branch slice (hides HBM latency under GEMM2+epilogue)
        if (d < 7) {
            #pragma unroll
            for (int i = 0; i < 4; ++i)
                pf[i] = *(const float4*)(brn + (size_t)(4 * rk + i) * 512 + (d + 1) * 64 + 4 * rc);
        }

        // GEMM2: O = T @ WsF ; epilogue: + y + bias, lrelu, store
        bf16x8 at0 = *(const bf16x8*)&Ts[(16 * w + l15) * LDP + l4 * 8];
        bf16x8 at1 = *(const bf16x8*)&Ts[(16 * w + l15) * LDP + 32 + l4 * 8];
        #pragma unroll
        for (int ft = 0; ft < 4; ++ft) {
            f32x4 o = {0.f, 0.f, 0.f, 0.f};
            o = __builtin_amdgcn_mfma_f32_16x16x32_bf16(at0, wfrag[ft][0], o, 0, 0, 0);
            o = __builtin_amdgcn_mfma_f32_16x16x32_bf16(at1, wfrag[ft][1], o, 0, 0, 0);
            const float bv = bias[d * 64 + 16 * ft + l15];
            #pragma unroll
            for (int r = 0; r < 4; ++r) {
                float val = o[r] + y[ft][r] + bv;
                val = fmaxf(val, 0.2f * val);
                out[(size_t)(16 * w + 4 * l4 + r) * 262144 + (size_t)(n * 8 + d) * 64 + 16 * ft + l15] = val;
            }
        }
        __syncthreads();
    }
}

extern "C" void kernel_launch(void* const* d_in, const int* in_sizes, int n_in,
                              void* d_out, int out_size, void* d_ws, size_t ws_size,
                              hipStream_t stream) {
    (void)in_sizes; (void)n_in; (void)out_size; (void)ws_size;
    const float* x0     = (const float*)d_in[0];
    const float* W0     = (const float*)d_in[1];
    const float* x1     = (const float*)d_in[2];
    const float* W1     = (const float*)d_in[3];
    const float* x2     = (const float*)d_in[4];
    const float* W2     = (const float*)d_in[5];
    const float* x3     = (const float*)d_in[6];
    const float* W3     = (const float*)d_in[7];
    const float* branch = (const float*)d_in[8];
    const float* Ws1    = (const float*)d_in[9];
    const float* Ws2    = (const float*)d_in[10];
    const float* bias   = (const float*)d_in[11];

    float* ylow = (float*)d_ws;                                          // 1 MiB fp32
    unsigned short* wsW = (unsigned short*)((char*)d_ws + (size_t)64 * 64 * 64 * 4);  // 8 KiB bf16
    float* out = (float*)d_out;

    tree_prep<<<128, 256, 0, stream>>>(x0, W0, x1, W1, x2, W2, Ws1, Ws2, ylow, wsW);
    tree_main<<<512, 256, 0, stream>>>(x3, W3, branch, bias, ylow, wsW, out);
}